// Round 2
// baseline (4077.834 us; speedup 1.0000x reference)
//
#include <hip/hip_runtime.h>
#include <hip/hip_bf16.h>

constexpr int kB  = 8;
constexpr int kC  = 256;
constexpr int kCq = 32;
constexpr int kH  = 96;
constexpr int kW  = 96;
constexpr int kP  = kH * kW;      // 9216
constexpr float kNEG = -1e30f;

// ---------------------------------------------------------------------------
// Kernel A: q/k/v projections for ONE stream, output pixel-major.
// grid (P/32, 8 = b, 5 = ochunk), block 256 = 8 og x 32 p.
// oc 0 -> q (o<32) + k (o>=32) from in_qk; oc 1..4 -> v rows from in_v.
// ---------------------------------------------------------------------------
__global__ __launch_bounds__(256) void qkv_proj(
    const float* __restrict__ in_qk, const float* __restrict__ in_v,
    const float* __restrict__ Wq, const float* __restrict__ bq,
    const float* __restrict__ Wk, const float* __restrict__ bk,
    const float* __restrict__ Wv, const float* __restrict__ bv,
    float* __restrict__ Q, float* __restrict__ K, float* __restrict__ V)
{
    const int pt = blockIdx.x;
    const int b  = blockIdx.y;
    const int oc = blockIdx.z;
    const int t = threadIdx.x;
    const int pl = t & 31;
    const int og = t >> 5;
    const int p = pt * 32 + pl;
    const float* __restrict__ in = (oc == 0 ? in_qk : in_v) + (size_t)b * kC * kP;

    const float4* w4[8];
    float acc[8];
    float* outp[8];
#pragma unroll
    for (int j = 0; j < 8; j++) {
        int ol = og + 8 * j;
        if (oc == 0) {
            if (ol < 32) {
                w4[j] = (const float4*)(Wq + (size_t)ol * kC);
                acc[j] = bq[ol];
                outp[j] = Q + ((size_t)b * kP + p) * kCq + ol;
            } else {
                w4[j] = (const float4*)(Wk + (size_t)(ol - 32) * kC);
                acc[j] = bk[ol - 32];
                outp[j] = K + ((size_t)b * kP + p) * kCq + (ol - 32);
            }
        } else {
            int ov = (oc - 1) * 64 + ol;
            w4[j] = (const float4*)(Wv + (size_t)ov * kC);
            acc[j] = bv[ov];
            outp[j] = V + ((size_t)b * kP + p) * kC + ov;
        }
    }
    for (int c = 0; c < kC; c += 4) {
        float x0 = in[(size_t)(c + 0) * kP + p];
        float x1 = in[(size_t)(c + 1) * kP + p];
        float x2 = in[(size_t)(c + 2) * kP + p];
        float x3 = in[(size_t)(c + 3) * kP + p];
#pragma unroll
        for (int j = 0; j < 8; j++) {
            float4 w = w4[j][c >> 2];
            acc[j] += w.x * x0 + w.y * x1 + w.z * x2 + w.w * x3;
        }
    }
#pragma unroll
    for (int j = 0; j < 8; j++) *outp[j] = acc[j];
}

// ---------------------------------------------------------------------------
// Kernel B: pass1 (one stream). grid (W/32, H, B), block 256.
// 192 scores -> softmax -> store (m, 1/sum) stats -> outW + epilogue:
// Zb[b][p][s_off+c] = bf16(gamma*outW + residual).  LDS: 63.1 KB.
// ---------------------------------------------------------------------------
__global__ __launch_bounds__(256) void cc_pass1(
    const float* __restrict__ Q, const float* __restrict__ K, const float* __restrict__ V,
    const float* __restrict__ res_in, const float* __restrict__ gamma_p,
    __hip_bfloat16* __restrict__ Zb, float* __restrict__ Sm, float* __restrict__ Si,
    int s_off)
{
    __shared__ __align__(16) float qs[32][33];
    __shared__ __align__(16) float sc[32][196];
    __shared__ __align__(16) float rs[256][33];
    const int wt = blockIdx.x, h = blockIdx.y, b = blockIdx.z;
    const int w0 = wt * 32;
    const int t = threadIdx.x;
    const size_t bP = (size_t)b * kP;

    for (int l = t; l < 32 * 32; l += 256) {
        int i = l >> 5, c = l & 31;
        qs[i][c] = Q[(bP + (size_t)h * kW + w0 + i) * kCq + c];
    }
    const float* __restrict__ res = res_in + (size_t)b * kC * kP + (size_t)h * kW + w0;
    for (int l = t; l < 256 * 32; l += 256) {
        int c2 = l >> 5, i2 = l & 31;
        rs[c2][i2] = res[(size_t)c2 * kP + i2];
    }
    __syncthreads();

    {   // scores: i = pixel-in-tile, sg = score slice
        const int i = t & 31, sg = t >> 5;
        for (int jj = sg; jj < 192; jj += 8) {
            const float* krow;
            if (jj < 96) krow = K + (bP + (size_t)jj * kW + w0 + i) * kCq;     // eH
            else         krow = K + (bP + (size_t)h * kW + (jj - 96)) * kCq;   // eW
            const float4* k4 = (const float4*)krow;
            float dot = 0.f;
#pragma unroll
            for (int c4 = 0; c4 < 8; c4++) {
                float4 kk = k4[c4];
                dot += kk.x * qs[i][c4 * 4 + 0] + kk.y * qs[i][c4 * 4 + 1]
                     + kk.z * qs[i][c4 * 4 + 2] + kk.w * qs[i][c4 * 4 + 3];
            }
            if (jj == h) dot = kNEG;   // eH diagonal mask (jj<96 range only, h<96)
            sc[i][jj] = dot;
        }
    }
    __syncthreads();

    {   // softmax over 192, 8 threads per pixel; record stats for pass2
        const int pi = t >> 3, sub = t & 7;
        float m = -3.0e38f;
        for (int j = sub; j < 192; j += 8) m = fmaxf(m, sc[pi][j]);
#pragma unroll
        for (int k = 1; k < 8; k <<= 1) m = fmaxf(m, __shfl_xor(m, k, 8));
        float ss = 0.f;
        for (int j = sub; j < 192; j += 8) ss += __expf(sc[pi][j] - m);
#pragma unroll
        for (int k = 1; k < 8; k <<= 1) ss += __shfl_xor(ss, k, 8);
        float inv = 1.0f / ss;
        for (int j = sub; j < 192; j += 8) sc[pi][j] = __expf(sc[pi][j] - m) * inv;
        if (sub == 0) {
            Sm[bP + (size_t)h * kW + w0 + pi] = m;
            Si[bP + (size_t)h * kW + w0 + pi] = inv;
        }
    }
    __syncthreads();

    // outW: thread = channel c, 32 pixel accumulators
    const int c = t;
    float acc[32];
#pragma unroll
    for (int i2 = 0; i2 < 32; i2++) acc[i2] = 0.f;
    const float* __restrict__ vrow = V + (bP + (size_t)h * kW) * kC + c;
    for (int j = 0; j < 96; j += 4) {
        float v0 = vrow[(size_t)(j + 0) * kC];
        float v1 = vrow[(size_t)(j + 1) * kC];
        float v2 = vrow[(size_t)(j + 2) * kC];
        float v3 = vrow[(size_t)(j + 3) * kC];
#pragma unroll
        for (int i2 = 0; i2 < 32; i2++) {
            float4 a4 = *(const float4*)&sc[i2][96 + j];
            acc[i2] += a4.x * v0 + a4.y * v1 + a4.z * v2 + a4.w * v3;
        }
    }
    const float gamma = gamma_p[0];
#pragma unroll
    for (int i2 = 0; i2 < 32; i2++) {
        Zb[(bP + (size_t)h * kW + w0 + i2) * 512 + s_off + c] =
            __float2bfloat16(gamma * acc[i2] + rs[c][i2]);
    }
}

// ---------------------------------------------------------------------------
// Kernel C: pass2 (one stream). grid (H/32, W, B), block 256.
// Recomputes the 96 eH scores from Q,K + stored stats (no AH buffer),
// then outH column aggregation; Zb += bf16(gamma*outH). LDS: 31.2 KB.
// ---------------------------------------------------------------------------
__global__ __launch_bounds__(256) void cc_pass2(
    const float* __restrict__ Q, const float* __restrict__ K, const float* __restrict__ V,
    const float* __restrict__ gamma_p,
    __hip_bfloat16* __restrict__ Zb, const float* __restrict__ Sm, const float* __restrict__ Si,
    int s_off)
{
    __shared__ __align__(16) float qs2[32][36];
    __shared__ __align__(16) float ks2[96][36];
    __shared__ __align__(16) float ah[32][100];
    const int ht = blockIdx.x, w = blockIdx.y, b = blockIdx.z;
    const int h0 = ht * 32;
    const int t = threadIdx.x;
    const size_t bP = (size_t)b * kP;

    for (int l = t; l < 32 * 32; l += 256) {
        int i = l >> 5, c = l & 31;
        qs2[i][c] = Q[(bP + (size_t)(h0 + i) * kW + w) * kCq + c];
    }
    for (int l = t; l < 96 * 32; l += 256) {
        int j = l >> 5, c = l & 31;
        ks2[j][c] = K[(bP + (size_t)j * kW + w) * kCq + c];
    }
    __syncthreads();

    {   // recompute eH scores + softmax weights via stats
        const int i = t & 31, jg = t >> 5;
        const float mi = Sm[bP + (size_t)(h0 + i) * kW + w];
        const float ii = Si[bP + (size_t)(h0 + i) * kW + w];
        for (int j = jg; j < 96; j += 8) {
            float dot = 0.f;
#pragma unroll
            for (int c4 = 0; c4 < 8; c4++) {
                float4 qq = *(const float4*)&qs2[i][c4 * 4];
                float4 kk = *(const float4*)&ks2[j][c4 * 4];
                dot += qq.x * kk.x + qq.y * kk.y + qq.z * kk.z + qq.w * kk.w;
            }
            ah[i][j] = (j == h0 + i) ? 0.f : __expf(dot - mi) * ii;
        }
    }
    __syncthreads();

    const int c = t;
    float acc[32];
#pragma unroll
    for (int i = 0; i < 32; i++) acc[i] = 0.f;
    const float* __restrict__ vcol = V + (bP + (size_t)w) * kC + c;
    for (int j = 0; j < 96; j += 4) {
        float v0 = vcol[(size_t)(j + 0) * kW * kC];
        float v1 = vcol[(size_t)(j + 1) * kW * kC];
        float v2 = vcol[(size_t)(j + 2) * kW * kC];
        float v3 = vcol[(size_t)(j + 3) * kW * kC];
#pragma unroll
        for (int i = 0; i < 32; i++) {
            float4 a4 = *(const float4*)&ah[i][j];
            acc[i] += a4.x * v0 + a4.y * v1 + a4.z * v2 + a4.w * v3;
        }
    }
    const float gamma = gamma_p[0];
#pragma unroll
    for (int i = 0; i < 32; i++) {
        size_t zi = (bP + (size_t)(h0 + i) * kW + w) * 512 + s_off + c;
        Zb[zi] = __float2bfloat16(__bfloat162float(Zb[zi]) + gamma * acc[i]);
    }
}

// ---------------------------------------------------------------------------
// Kernel D: fused depthwise 3x3 + pointwise 512->256 + bias + leaky relu.
// grid (W/16, H, B), block 256. z2 tile (16 px x 512 ch) lives in LDS
// (row stride 520 floats -> only 2-way b128 bank aliasing = free).
// ---------------------------------------------------------------------------
__global__ __launch_bounds__(256) void dwpw(
    const __hip_bfloat16* __restrict__ Zb,
    const float* __restrict__ Wdw, const float* __restrict__ bd,
    const float* __restrict__ Wp, const float* __restrict__ bp,
    float* __restrict__ out)
{
    __shared__ __align__(16) float zs[16][520];
    const int wt = blockIdx.x, h = blockIdx.y, b = blockIdx.z;
    const int w0 = wt * 16;
    const int t = threadIdx.x;
    const size_t bP = (size_t)b * kP;

#pragma unroll
    for (int half = 0; half < 2; half++) {
        const int c = t + half * 256;
        float wdv[9];
#pragma unroll
        for (int k = 0; k < 9; k++) wdv[k] = Wdw[c * 9 + k];
        const float bias = bd[c];
        for (int i = 0; i < 16; i++) {
            const int w = w0 + i;
            float acc = bias;
#pragma unroll
            for (int dh = -1; dh <= 1; dh++) {
                const int hh = h + dh;
                if (hh < 0 || hh >= kH) continue;
#pragma unroll
                for (int dw = -1; dw <= 1; dw++) {
                    const int ww = w + dw;
                    if (ww < 0 || ww >= kW) continue;
                    acc += wdv[(dh + 1) * 3 + (dw + 1)] *
                           __bfloat162float(Zb[(bP + (size_t)hh * kW + ww) * 512 + c]);
                }
            }
            zs[i][c] = acc;
        }
    }
    __syncthreads();

    // pointwise: p = pixel-in-tile (16), og = output group (16), 16 outputs each
    const int p = t & 15, og = t >> 4;
    float acc[16];
#pragma unroll
    for (int j = 0; j < 16; j++) acc[j] = bp[og * 16 + j];
    const float4* __restrict__ wbase = (const float4*)(Wp + (size_t)og * 16 * 512);
    for (int c4 = 0; c4 < 128; c4++) {
        float4 zv = *(const float4*)&zs[p][c4 * 4];
#pragma unroll
        for (int j = 0; j < 16; j++) {
            float4 wv = wbase[j * 128 + c4];
            acc[j] += wv.x * zv.x + wv.y * zv.y + wv.z * zv.z + wv.w * zv.w;
        }
    }
#pragma unroll
    for (int j = 0; j < 16; j++) {
        const int o = og * 16 + j;
        float v = acc[j];
        out[((size_t)b * 256 + o) * kP + (size_t)h * kW + w0 + p] =
            v > 0.f ? v : 0.01f * v;
    }
}

// ---------------------------------------------------------------------------
extern "C" void kernel_launch(void* const* d_in, const int* in_sizes, int n_in,
                              void* d_out, int out_size, void* d_ws, size_t ws_size,
                              hipStream_t stream)
{
    const float* x   = (const float*)d_in[0];
    const float* y   = (const float*)d_in[1];
    const float* Wq  = (const float*)d_in[2];
    const float* bq  = (const float*)d_in[3];
    const float* Wk  = (const float*)d_in[4];
    const float* bk  = (const float*)d_in[5];
    const float* Wv  = (const float*)d_in[6];
    const float* bv  = (const float*)d_in[7];
    const float* g1  = (const float*)d_in[8];
    const float* g2  = (const float*)d_in[9];
    const float* Wdw = (const float*)d_in[10];
    const float* bd  = (const float*)d_in[11];
    const float* Wp  = (const float*)d_in[12];
    const float* bp  = (const float*)d_in[13];
    float* out = (float*)d_out;

    // Workspace layout (90.6 MB total):
    //   Zb  : bf16 [8][9216][512]  = 75,497,472 B
    //   Q,K : fp32 [8][9216][32]   =  9,437,184 B each  (reused per stream)
    //   Sm,Si: fp32 [8][9216]      =    294,912 B each  (softmax stats)
    // V (fp32 [8][9216][256] = 72 MB) lives in d_out until the final kernel.
    char* wsb = (char*)d_ws;
    __hip_bfloat16* Zb = (__hip_bfloat16*)wsb;
    float* Q  = (float*)(wsb + 75497472);
    float* K  = (float*)(wsb + 75497472 + 9437184);
    float* Sm = (float*)(wsb + 75497472 + 2 * 9437184);
    float* Si = (float*)(wsb + 75497472 + 2 * 9437184 + 294912);
    float* V  = out;

    // stream 1: q,k from x; v from y; residual x; channels [0,256)
    hipLaunchKernelGGL(qkv_proj, dim3(kP / 32, kB, 5), dim3(256), 0, stream,
                       x, y, Wq, bq, Wk, bk, Wv, bv, Q, K, V);
    hipLaunchKernelGGL(cc_pass1, dim3(kW / 32, kH, kB), dim3(256), 0, stream,
                       Q, K, V, x, g1, Zb, Sm, Si, 0);
    hipLaunchKernelGGL(cc_pass2, dim3(kH / 32, kW, kB), dim3(256), 0, stream,
                       Q, K, V, g1, Zb, Sm, Si, 0);
    // stream 2: q,k from y; v from x; residual y; channels [256,512)
    hipLaunchKernelGGL(qkv_proj, dim3(kP / 32, kB, 5), dim3(256), 0, stream,
                       y, x, Wq, bq, Wk, bk, Wv, bv, Q, K, V);
    hipLaunchKernelGGL(cc_pass1, dim3(kW / 32, kH, kB), dim3(256), 0, stream,
                       Q, K, V, y, g2, Zb, Sm, Si, 256);
    hipLaunchKernelGGL(cc_pass2, dim3(kH / 32, kW, kB), dim3(256), 0, stream,
                       Q, K, V, g2, Zb, Sm, Si, 256);
    // fused depthwise + pointwise + leaky relu (overwrites d_out; V is dead)
    hipLaunchKernelGGL(dwpw, dim3(kW / 16, kH, kB), dim3(256), 0, stream,
                       Zb, Wdw, bd, Wp, bp, out);
}

// Round 3
// 3053.941 us; speedup vs baseline: 1.3353x; 1.3353x over previous
//
#include <hip/hip_runtime.h>
#include <hip/hip_bf16.h>

constexpr int kB  = 8;
constexpr int kC  = 256;
constexpr int kCq = 32;
constexpr int kH  = 96;
constexpr int kW  = 96;
constexpr int kP  = kH * kW;      // 9216
constexpr float kNEG = -1e30f;

using bf16x8 = __attribute__((ext_vector_type(8))) short;
using f32x4  = __attribute__((ext_vector_type(4))) float;

// ---------------------------------------------------------------------------
// Kernel A: q/k/v projections for ONE stream, output pixel-major.
// grid (P/32, 8 = b, 5 = ochunk), block 256 = 8 og x 32 p.
// oc 0 -> q (o<32) + k (o>=32) from in_qk; oc 1..4 -> v rows from in_v.
// ---------------------------------------------------------------------------
__global__ __launch_bounds__(256) void qkv_proj(
    const float* __restrict__ in_qk, const float* __restrict__ in_v,
    const float* __restrict__ Wq, const float* __restrict__ bq,
    const float* __restrict__ Wk, const float* __restrict__ bk,
    const float* __restrict__ Wv, const float* __restrict__ bv,
    float* __restrict__ Q, float* __restrict__ K, float* __restrict__ V)
{
    const int pt = blockIdx.x;
    const int b  = blockIdx.y;
    const int oc = blockIdx.z;
    const int t = threadIdx.x;
    const int pl = t & 31;
    const int og = t >> 5;
    const int p = pt * 32 + pl;
    const float* __restrict__ in = (oc == 0 ? in_qk : in_v) + (size_t)b * kC * kP;

    const float4* w4[8];
    float acc[8];
    float* outp[8];
#pragma unroll
    for (int j = 0; j < 8; j++) {
        int ol = og + 8 * j;
        if (oc == 0) {
            if (ol < 32) {
                w4[j] = (const float4*)(Wq + (size_t)ol * kC);
                acc[j] = bq[ol];
                outp[j] = Q + ((size_t)b * kP + p) * kCq + ol;
            } else {
                w4[j] = (const float4*)(Wk + (size_t)(ol - 32) * kC);
                acc[j] = bk[ol - 32];
                outp[j] = K + ((size_t)b * kP + p) * kCq + (ol - 32);
            }
        } else {
            int ov = (oc - 1) * 64 + ol;
            w4[j] = (const float4*)(Wv + (size_t)ov * kC);
            acc[j] = bv[ov];
            outp[j] = V + ((size_t)b * kP + p) * kC + ov;
        }
    }
    for (int c = 0; c < kC; c += 4) {
        float x0 = in[(size_t)(c + 0) * kP + p];
        float x1 = in[(size_t)(c + 1) * kP + p];
        float x2 = in[(size_t)(c + 2) * kP + p];
        float x3 = in[(size_t)(c + 3) * kP + p];
#pragma unroll
        for (int j = 0; j < 8; j++) {
            float4 w = w4[j][c >> 2];
            acc[j] += w.x * x0 + w.y * x1 + w.z * x2 + w.w * x3;
        }
    }
#pragma unroll
    for (int j = 0; j < 8; j++) *outp[j] = acc[j];
}

// ---------------------------------------------------------------------------
// Kernel B: pass1 (one stream). grid (W/32, H, B), block 256.
// 192 scores -> softmax -> store (m, 1/sum) stats -> outW + epilogue:
// Zb[b][p][s_off+c] = bf16(gamma*outW + residual).  LDS: 63.1 KB.
// ---------------------------------------------------------------------------
__global__ __launch_bounds__(256) void cc_pass1(
    const float* __restrict__ Q, const float* __restrict__ K, const float* __restrict__ V,
    const float* __restrict__ res_in, const float* __restrict__ gamma_p,
    __hip_bfloat16* __restrict__ Zb, float* __restrict__ Sm, float* __restrict__ Si,
    int s_off)
{
    __shared__ __align__(16) float qs[32][33];
    __shared__ __align__(16) float sc[32][196];
    __shared__ __align__(16) float rs[256][33];
    const int wt = blockIdx.x, h = blockIdx.y, b = blockIdx.z;
    const int w0 = wt * 32;
    const int t = threadIdx.x;
    const size_t bP = (size_t)b * kP;

    for (int l = t; l < 32 * 32; l += 256) {
        int i = l >> 5, c = l & 31;
        qs[i][c] = Q[(bP + (size_t)h * kW + w0 + i) * kCq + c];
    }
    const float* __restrict__ res = res_in + (size_t)b * kC * kP + (size_t)h * kW + w0;
    for (int l = t; l < 256 * 32; l += 256) {
        int c2 = l >> 5, i2 = l & 31;
        rs[c2][i2] = res[(size_t)c2 * kP + i2];
    }
    __syncthreads();

    {   // scores: i = pixel-in-tile, sg = score slice
        const int i = t & 31, sg = t >> 5;
        for (int jj = sg; jj < 192; jj += 8) {
            const float* krow;
            if (jj < 96) krow = K + (bP + (size_t)jj * kW + w0 + i) * kCq;     // eH
            else         krow = K + (bP + (size_t)h * kW + (jj - 96)) * kCq;   // eW
            const float4* k4 = (const float4*)krow;
            float dot = 0.f;
#pragma unroll
            for (int c4 = 0; c4 < 8; c4++) {
                float4 kk = k4[c4];
                dot += kk.x * qs[i][c4 * 4 + 0] + kk.y * qs[i][c4 * 4 + 1]
                     + kk.z * qs[i][c4 * 4 + 2] + kk.w * qs[i][c4 * 4 + 3];
            }
            if (jj == h) dot = kNEG;   // eH diagonal mask (jj<96 range only, h<96)
            sc[i][jj] = dot;
        }
    }
    __syncthreads();

    {   // softmax over 192, 8 threads per pixel; record stats for pass2
        const int pi = t >> 3, sub = t & 7;
        float m = -3.0e38f;
        for (int j = sub; j < 192; j += 8) m = fmaxf(m, sc[pi][j]);
#pragma unroll
        for (int k = 1; k < 8; k <<= 1) m = fmaxf(m, __shfl_xor(m, k, 8));
        float ss = 0.f;
        for (int j = sub; j < 192; j += 8) ss += __expf(sc[pi][j] - m);
#pragma unroll
        for (int k = 1; k < 8; k <<= 1) ss += __shfl_xor(ss, k, 8);
        float inv = 1.0f / ss;
        for (int j = sub; j < 192; j += 8) sc[pi][j] = __expf(sc[pi][j] - m) * inv;
        if (sub == 0) {
            Sm[bP + (size_t)h * kW + w0 + pi] = m;
            Si[bP + (size_t)h * kW + w0 + pi] = inv;
        }
    }
    __syncthreads();

    // outW: thread = channel c, 32 pixel accumulators
    const int c = t;
    float acc[32];
#pragma unroll
    for (int i2 = 0; i2 < 32; i2++) acc[i2] = 0.f;
    const float* __restrict__ vrow = V + (bP + (size_t)h * kW) * kC + c;
    for (int j = 0; j < 96; j += 4) {
        float v0 = vrow[(size_t)(j + 0) * kC];
        float v1 = vrow[(size_t)(j + 1) * kC];
        float v2 = vrow[(size_t)(j + 2) * kC];
        float v3 = vrow[(size_t)(j + 3) * kC];
#pragma unroll
        for (int i2 = 0; i2 < 32; i2++) {
            float4 a4 = *(const float4*)&sc[i2][96 + j];
            acc[i2] += a4.x * v0 + a4.y * v1 + a4.z * v2 + a4.w * v3;
        }
    }
    const float gamma = gamma_p[0];
#pragma unroll
    for (int i2 = 0; i2 < 32; i2++) {
        Zb[(bP + (size_t)h * kW + w0 + i2) * 512 + s_off + c] =
            __float2bfloat16(gamma * acc[i2] + rs[c][i2]);
    }
}

// ---------------------------------------------------------------------------
// Kernel C: pass2 (one stream). grid (H/32, W, B), block 256.
// Recomputes the 96 eH scores from Q,K + stored stats (no AH buffer),
// then outH column aggregation; Zb += bf16(gamma*outH). LDS: 31.2 KB.
// ---------------------------------------------------------------------------
__global__ __launch_bounds__(256) void cc_pass2(
    const float* __restrict__ Q, const float* __restrict__ K, const float* __restrict__ V,
    const float* __restrict__ gamma_p,
    __hip_bfloat16* __restrict__ Zb, const float* __restrict__ Sm, const float* __restrict__ Si,
    int s_off)
{
    __shared__ __align__(16) float qs2[32][36];
    __shared__ __align__(16) float ks2[96][36];
    __shared__ __align__(16) float ah[32][100];
    const int ht = blockIdx.x, w = blockIdx.y, b = blockIdx.z;
    const int h0 = ht * 32;
    const int t = threadIdx.x;
    const size_t bP = (size_t)b * kP;

    for (int l = t; l < 32 * 32; l += 256) {
        int i = l >> 5, c = l & 31;
        qs2[i][c] = Q[(bP + (size_t)(h0 + i) * kW + w) * kCq + c];
    }
    for (int l = t; l < 96 * 32; l += 256) {
        int j = l >> 5, c = l & 31;
        ks2[j][c] = K[(bP + (size_t)j * kW + w) * kCq + c];
    }
    __syncthreads();

    {   // recompute eH scores + softmax weights via stats
        const int i = t & 31, jg = t >> 5;
        const float mi = Sm[bP + (size_t)(h0 + i) * kW + w];
        const float ii = Si[bP + (size_t)(h0 + i) * kW + w];
        for (int j = jg; j < 96; j += 8) {
            float dot = 0.f;
#pragma unroll
            for (int c4 = 0; c4 < 8; c4++) {
                float4 qq = *(const float4*)&qs2[i][c4 * 4];
                float4 kk = *(const float4*)&ks2[j][c4 * 4];
                dot += qq.x * kk.x + qq.y * kk.y + qq.z * kk.z + qq.w * kk.w;
            }
            ah[i][j] = (j == h0 + i) ? 0.f : __expf(dot - mi) * ii;
        }
    }
    __syncthreads();

    const int c = t;
    float acc[32];
#pragma unroll
    for (int i = 0; i < 32; i++) acc[i] = 0.f;
    const float* __restrict__ vcol = V + (bP + (size_t)w) * kC + c;
    for (int j = 0; j < 96; j += 4) {
        float v0 = vcol[(size_t)(j + 0) * kW * kC];
        float v1 = vcol[(size_t)(j + 1) * kW * kC];
        float v2 = vcol[(size_t)(j + 2) * kW * kC];
        float v3 = vcol[(size_t)(j + 3) * kW * kC];
#pragma unroll
        for (int i = 0; i < 32; i++) {
            float4 a4 = *(const float4*)&ah[i][j];
            acc[i] += a4.x * v0 + a4.y * v1 + a4.z * v2 + a4.w * v3;
        }
    }
    const float gamma = gamma_p[0];
#pragma unroll
    for (int i = 0; i < 32; i++) {
        size_t zi = (bP + (size_t)(h0 + i) * kW + w) * 512 + s_off + c;
        Zb[zi] = __float2bfloat16(__bfloat162float(Zb[zi]) + gamma * acc[i]);
    }
}

// ---------------------------------------------------------------------------
// Kernel W: convert Wp [256][512] fp32 -> bf16 (into dead Q region of ws).
// ---------------------------------------------------------------------------
__global__ __launch_bounds__(256) void wp_convert(
    const float* __restrict__ Wp, __hip_bfloat16* __restrict__ Wpb)
{
    const int i = blockIdx.x * 256 + threadIdx.x;
    Wpb[i] = __float2bfloat16(Wp[i]);
}

// ---------------------------------------------------------------------------
// Kernel D: fused depthwise 3x3 + pointwise 512->256 (bf16 MFMA) + leaky relu.
// grid (W/32, H, B), block 256 = 4 waves.
// Phase 1: depthwise -> bf16 z tile [32 px][512 ch] in LDS (stride 520 bf16).
// Phase 2: MFMA 16x16x32: per wave 2 m-tiles (px) x 4 n-tiles (out ch of its
//          64-wide slice), K = 512. B fragments straight from L2-resident Wpb.
// Phase 3: epilogue via LDS transpose (reuses z region) -> coalesced stores.
// MFMA layouts (m89/m91/m120-verified): A[m=lane&15][k=quad*8+j],
// B[k=quad*8+j][n=lane&15], D: col=lane&15, row=quad*4+reg.
// ---------------------------------------------------------------------------
__global__ __launch_bounds__(256) void dwpw(
    const __hip_bfloat16* __restrict__ Zb,
    const float* __restrict__ Wdw, const float* __restrict__ bd,
    const __hip_bfloat16* __restrict__ Wpb, const float* __restrict__ bp,
    float* __restrict__ out)
{
    __shared__ __align__(16) char smem[33792];
    __hip_bfloat16 (*zs)[520] = (__hip_bfloat16 (*)[520])smem;

    const int wt = blockIdx.x, h = blockIdx.y, b = blockIdx.z;
    const int w0 = wt * 32;
    const int t = threadIdx.x;
    const size_t bP = (size_t)b * kP;

    // ---- phase 1: depthwise 3x3, thread t owns channel pair (2t, 2t+1) ----
    {
        float wd0[9], wd1[9];
#pragma unroll
        for (int k = 0; k < 9; k++) {
            wd0[k] = Wdw[(size_t)(2 * t) * 9 + k];
            wd1[k] = Wdw[(size_t)(2 * t + 1) * 9 + k];
        }
        const float b0 = bd[2 * t], b1 = bd[2 * t + 1];
        const __hip_bfloat162* __restrict__ Zp =
            (const __hip_bfloat162*)Zb + bP * 256 + t;
        for (int i = 0; i < 32; i++) {
            float a0 = b0, a1 = b1;
#pragma unroll
            for (int dh = -1; dh <= 1; dh++) {
                const int hh = h + dh;
                if (hh < 0 || hh >= kH) continue;
#pragma unroll
                for (int dw = -1; dw <= 1; dw++) {
                    const int ww = w0 + i + dw;
                    if (ww < 0 || ww >= kW) continue;
                    __hip_bfloat162 z2 = Zp[(size_t)(hh * kW + ww) * 256];
                    const int k = (dh + 1) * 3 + (dw + 1);
                    a0 += wd0[k] * __bfloat162float(z2.x);
                    a1 += wd1[k] * __bfloat162float(z2.y);
                }
            }
            __hip_bfloat162 pz;
            pz.x = __float2bfloat16(a0);
            pz.y = __float2bfloat16(a1);
            ((__hip_bfloat162*)&zs[i][0])[t] = pz;
        }
    }
    __syncthreads();

    // ---- phase 2: pointwise MFMA ----
    const int l = t & 63, wv = t >> 6;
    const int lo16 = l & 15, q = l >> 4;   // quad 0..3

    f32x4 acc[2][4];
#pragma unroll
    for (int mt = 0; mt < 2; mt++)
#pragma unroll
        for (int nt = 0; nt < 4; nt++) acc[mt][nt] = (f32x4)0.f;

    const bf16x8* __restrict__ Bb[4];
#pragma unroll
    for (int nt = 0; nt < 4; nt++)
        Bb[nt] = (const bf16x8*)(Wpb + (size_t)(wv * 64 + nt * 16 + lo16) * 512);

    for (int kc = 0; kc < 16; kc++) {
        bf16x8 a0 = *(const bf16x8*)&zs[lo16][kc * 32 + q * 8];
        bf16x8 a1 = *(const bf16x8*)&zs[16 + lo16][kc * 32 + q * 8];
#pragma unroll
        for (int nt = 0; nt < 4; nt++) {
            bf16x8 bf = Bb[nt][kc * 4 + q];
            acc[0][nt] = __builtin_amdgcn_mfma_f32_16x16x32_bf16(a0, bf, acc[0][nt], 0, 0, 0);
            acc[1][nt] = __builtin_amdgcn_mfma_f32_16x16x32_bf16(a1, bf, acc[1][nt], 0, 0, 0);
        }
    }
    __syncthreads();   // all waves done reading zs; reuse smem for transpose

    // ---- phase 3: bias + leaky relu, LDS transpose, coalesced stores ----
    float* os = (float*)smem + (size_t)wv * 64 * 33;   // per-wave [64 o][33]
#pragma unroll
    for (int nt = 0; nt < 4; nt++) {
        const int ol = nt * 16 + lo16;
        const float bias = bp[wv * 64 + ol];
#pragma unroll
        for (int mt = 0; mt < 2; mt++) {
#pragma unroll
            for (int r = 0; r < 4; r++) {
                float v = acc[mt][nt][r] + bias;
                v = v > 0.f ? v : 0.01f * v;
                os[ol * 33 + mt * 16 + q * 4 + r] = v;
            }
        }
    }
    __syncthreads();
    const int px = l & 31, oh = l >> 5;    // 2 o-rows per iteration
    for (int j = 0; j < 32; j++) {
        const int ol = j * 2 + oh;
        out[((size_t)b * 256 + wv * 64 + ol) * kP + (size_t)h * kW + w0 + px] =
            os[ol * 33 + px];
    }
}

// ---------------------------------------------------------------------------
extern "C" void kernel_launch(void* const* d_in, const int* in_sizes, int n_in,
                              void* d_out, int out_size, void* d_ws, size_t ws_size,
                              hipStream_t stream)
{
    const float* x   = (const float*)d_in[0];
    const float* y   = (const float*)d_in[1];
    const float* Wq  = (const float*)d_in[2];
    const float* bq  = (const float*)d_in[3];
    const float* Wk  = (const float*)d_in[4];
    const float* bk  = (const float*)d_in[5];
    const float* Wv  = (const float*)d_in[6];
    const float* bv  = (const float*)d_in[7];
    const float* g1  = (const float*)d_in[8];
    const float* g2  = (const float*)d_in[9];
    const float* Wdw = (const float*)d_in[10];
    const float* bd  = (const float*)d_in[11];
    const float* Wp  = (const float*)d_in[12];
    const float* bp  = (const float*)d_in[13];
    float* out = (float*)d_out;

    // Workspace layout (90.6 MB total):
    //   Zb  : bf16 [8][9216][512]  = 75,497,472 B
    //   Q,K : fp32 [8][9216][32]   =  9,437,184 B each  (reused per stream)
    //   Sm,Si: fp32 [8][9216]      =    294,912 B each  (softmax stats)
    // V (fp32 [8][9216][256] = 72 MB) lives in d_out until the final kernel.
    // Wpb (bf16, 256 KB) reuses the Q region after the last cc_pass2.
    char* wsb = (char*)d_ws;
    __hip_bfloat16* Zb = (__hip_bfloat16*)wsb;
    float* Q  = (float*)(wsb + 75497472);
    float* K  = (float*)(wsb + 75497472 + 9437184);
    float* Sm = (float*)(wsb + 75497472 + 2 * 9437184);
    float* Si = (float*)(wsb + 75497472 + 2 * 9437184 + 294912);
    __hip_bfloat16* Wpb = (__hip_bfloat16*)(wsb + 75497472);  // dead Q region
    float* V  = out;

    // stream 1: q,k from x; v from y; residual x; channels [0,256)
    hipLaunchKernelGGL(qkv_proj, dim3(kP / 32, kB, 5), dim3(256), 0, stream,
                       x, y, Wq, bq, Wk, bk, Wv, bv, Q, K, V);
    hipLaunchKernelGGL(cc_pass1, dim3(kW / 32, kH, kB), dim3(256), 0, stream,
                       Q, K, V, x, g1, Zb, Sm, Si, 0);
    hipLaunchKernelGGL(cc_pass2, dim3(kH / 32, kW, kB), dim3(256), 0, stream,
                       Q, K, V, g1, Zb, Sm, Si, 0);
    // stream 2: q,k from y; v from x; residual y; channels [256,512)
    hipLaunchKernelGGL(qkv_proj, dim3(kP / 32, kB, 5), dim3(256), 0, stream,
                       y, x, Wq, bq, Wk, bk, Wv, bv, Q, K, V);
    hipLaunchKernelGGL(cc_pass1, dim3(kW / 32, kH, kB), dim3(256), 0, stream,
                       Q, K, V, y, g2, Zb, Sm, Si, 256);
    hipLaunchKernelGGL(cc_pass2, dim3(kH / 32, kW, kB), dim3(256), 0, stream,
                       Q, K, V, g2, Zb, Sm, Si, 256);
    // convert Wp to bf16 (Q region is dead now)
    hipLaunchKernelGGL(wp_convert, dim3(512), dim3(256), 0, stream, Wp, Wpb);
    // fused depthwise + pointwise MFMA + leaky relu (overwrites d_out)
    hipLaunchKernelGGL(dwpw, dim3(kW / 32, kH, kB), dim3(256), 0, stream,
                       Zb, Wdw, bd, Wpb, bp, out);
}

// Round 4
// 1440.391 us; speedup vs baseline: 2.8311x; 2.1202x over previous
//
#include <hip/hip_runtime.h>
#include <hip/hip_bf16.h>

constexpr int kB  = 8;
constexpr int kC  = 256;
constexpr int kCq = 32;
constexpr int kH  = 96;
constexpr int kW  = 96;
constexpr int kP  = kH * kW;      // 9216
constexpr float kNEG = -1e30f;

using bf16x8 = __attribute__((ext_vector_type(8))) short;
using f32x4  = __attribute__((ext_vector_type(4))) float;

// ---------------------------------------------------------------------------
// Kernel W1: convert Wq+Wk -> Wqkb [64][256] bf16, Wv -> Wvb [256][256] bf16.
// grid 320 x 256.
// ---------------------------------------------------------------------------
__global__ __launch_bounds__(256) void w_convert(
    const float* __restrict__ Wq, const float* __restrict__ Wk,
    const float* __restrict__ Wv,
    __hip_bfloat16* __restrict__ Wqkb, __hip_bfloat16* __restrict__ Wvb)
{
    const int i = blockIdx.x * 256 + threadIdx.x;
    if (i < 8192)       Wqkb[i] = __float2bfloat16(Wq[i]);
    else if (i < 16384) Wqkb[i] = __float2bfloat16(Wk[i - 8192]);
    else                Wvb[i - 16384] = __float2bfloat16(Wv[i - 16384]);
}

// ---------------------------------------------------------------------------
// Kernel A: q/k/v projection GEMM via bf16 MFMA, no LDS.
// D[m=o][n=p]: A = weights (bf16, contiguous frags), B = input (built from
// 8 channel-strided fp32 loads per lane; lanes n=0..15 -> 64B coalesced runs).
// grid (144, B), block 256 = 4 waves; per wave 16 pixels x 320 outputs.
// D: col=lane&15 = pixel, row=quad*4+reg = o -> float4 stores along channel.
// ---------------------------------------------------------------------------
__global__ __launch_bounds__(256) void qkv_mfma(
    const float* __restrict__ in_qk, const float* __restrict__ in_v,
    const __hip_bfloat16* __restrict__ Wqkb, const __hip_bfloat16* __restrict__ Wvb,
    const float* __restrict__ bq, const float* __restrict__ bk,
    const float* __restrict__ bv,
    float* __restrict__ Q, float* __restrict__ K, float* __restrict__ V)
{
    const int b = blockIdx.y;
    const int t = threadIdx.x;
    const int wv = t >> 6, l = t & 63;
    const int n = l & 15, q = l >> 4;            // n = pixel col, q = quad
    const int p = blockIdx.x * 64 + wv * 16 + n; // this lane's pixel
    const size_t bP = (size_t)b * kP;

    const float* __restrict__ xq = in_qk + (size_t)b * kC * kP + p;
    const float* __restrict__ xv = in_v  + (size_t)b * kC * kP + p;

    f32x4 acc[20];
#pragma unroll
    for (int i = 0; i < 20; i++) acc[i] = (f32x4)0.f;

    for (int kc = 0; kc < 8; kc++) {
        const int c0 = kc * 32 + q * 8;          // this lane's k-slice base
        // ---- B fragments: 16 scalar fp32 loads (all issued up front) ----
        float fq[8], fv[8];
#pragma unroll
        for (int j = 0; j < 8; j++) fq[j] = xq[(size_t)(c0 + j) * kP];
#pragma unroll
        for (int j = 0; j < 8; j++) fv[j] = xv[(size_t)(c0 + j) * kP];
        union { bf16x8 v; __hip_bfloat16 h[8]; } bfq, bfv;
#pragma unroll
        for (int j = 0; j < 8; j++) bfq.h[j] = __float2bfloat16(fq[j]);
#pragma unroll
        for (int j = 0; j < 8; j++) bfv.h[j] = __float2bfloat16(fv[j]);

        // ---- A fragments from bf16 weights + MFMA ----
#pragma unroll
        for (int mt = 0; mt < 4; mt++) {
            bf16x8 a = *(const bf16x8*)(Wqkb + ((mt * 16 + n) << 8) + c0);
            acc[mt] = __builtin_amdgcn_mfma_f32_16x16x32_bf16(a, bfq.v, acc[mt], 0, 0, 0);
        }
#pragma unroll
        for (int mt = 0; mt < 16; mt++) {
            bf16x8 a = *(const bf16x8*)(Wvb + ((mt * 16 + n) << 8) + c0);
            acc[4 + mt] = __builtin_amdgcn_mfma_f32_16x16x32_bf16(a, bfv.v, acc[4 + mt], 0, 0, 0);
        }
    }

    // ---- epilogue: bias + float4 stores (pixel-major Q/K/V) ----
    float* __restrict__ Qp = Q + (bP + p) * kCq;
    float* __restrict__ Kp = K + (bP + p) * kCq;
    float* __restrict__ Vp = V + (bP + p) * kC;
#pragma unroll
    for (int mt = 0; mt < 2; mt++) {
        float4 bias = *(const float4*)&bq[mt * 16 + q * 4];
        float4 r = { acc[mt][0] + bias.x, acc[mt][1] + bias.y,
                     acc[mt][2] + bias.z, acc[mt][3] + bias.w };
        *(float4*)&Qp[mt * 16 + q * 4] = r;
    }
#pragma unroll
    for (int mt = 2; mt < 4; mt++) {
        float4 bias = *(const float4*)&bk[(mt - 2) * 16 + q * 4];
        float4 r = { acc[mt][0] + bias.x, acc[mt][1] + bias.y,
                     acc[mt][2] + bias.z, acc[mt][3] + bias.w };
        *(float4*)&Kp[(mt - 2) * 16 + q * 4] = r;
    }
#pragma unroll
    for (int mt = 0; mt < 16; mt++) {
        float4 bias = *(const float4*)&bv[mt * 16 + q * 4];
        float4 r = { acc[4 + mt][0] + bias.x, acc[4 + mt][1] + bias.y,
                     acc[4 + mt][2] + bias.z, acc[4 + mt][3] + bias.w };
        *(float4*)&Vp[mt * 16 + q * 4] = r;
    }
}

// ---------------------------------------------------------------------------
// Kernel B: pass1 (one stream). grid (W/32, H, B), block 256.
// 192 scores -> softmax -> store (m, 1/sum) stats -> outW + epilogue:
// Zb[b][p][s_off+c] = bf16(gamma*outW + residual).  LDS: 63.1 KB.
// ---------------------------------------------------------------------------
__global__ __launch_bounds__(256) void cc_pass1(
    const float* __restrict__ Q, const float* __restrict__ K, const float* __restrict__ V,
    const float* __restrict__ res_in, const float* __restrict__ gamma_p,
    __hip_bfloat16* __restrict__ Zb, float* __restrict__ Sm, float* __restrict__ Si,
    int s_off)
{
    __shared__ __align__(16) float qs[32][33];
    __shared__ __align__(16) float sc[32][196];
    __shared__ __align__(16) float rs[256][33];
    const int wt = blockIdx.x, h = blockIdx.y, b = blockIdx.z;
    const int w0 = wt * 32;
    const int t = threadIdx.x;
    const size_t bP = (size_t)b * kP;

    for (int l = t; l < 32 * 32; l += 256) {
        int i = l >> 5, c = l & 31;
        qs[i][c] = Q[(bP + (size_t)h * kW + w0 + i) * kCq + c];
    }
    const float* __restrict__ res = res_in + (size_t)b * kC * kP + (size_t)h * kW + w0;
    for (int l = t; l < 256 * 32; l += 256) {
        int c2 = l >> 5, i2 = l & 31;
        rs[c2][i2] = res[(size_t)c2 * kP + i2];
    }
    __syncthreads();

    {   // scores: i = pixel-in-tile, sg = score slice
        const int i = t & 31, sg = t >> 5;
        for (int jj = sg; jj < 192; jj += 8) {
            const float* krow;
            if (jj < 96) krow = K + (bP + (size_t)jj * kW + w0 + i) * kCq;     // eH
            else         krow = K + (bP + (size_t)h * kW + (jj - 96)) * kCq;   // eW
            const float4* k4 = (const float4*)krow;
            float dot = 0.f;
#pragma unroll
            for (int c4 = 0; c4 < 8; c4++) {
                float4 kk = k4[c4];
                dot += kk.x * qs[i][c4 * 4 + 0] + kk.y * qs[i][c4 * 4 + 1]
                     + kk.z * qs[i][c4 * 4 + 2] + kk.w * qs[i][c4 * 4 + 3];
            }
            if (jj == h) dot = kNEG;   // eH diagonal mask (jj<96 range only, h<96)
            sc[i][jj] = dot;
        }
    }
    __syncthreads();

    {   // softmax over 192, 8 threads per pixel; record stats for pass2
        const int pi = t >> 3, sub = t & 7;
        float m = -3.0e38f;
        for (int j = sub; j < 192; j += 8) m = fmaxf(m, sc[pi][j]);
#pragma unroll
        for (int k = 1; k < 8; k <<= 1) m = fmaxf(m, __shfl_xor(m, k, 8));
        float ss = 0.f;
        for (int j = sub; j < 192; j += 8) ss += __expf(sc[pi][j] - m);
#pragma unroll
        for (int k = 1; k < 8; k <<= 1) ss += __shfl_xor(ss, k, 8);
        float inv = 1.0f / ss;
        for (int j = sub; j < 192; j += 8) sc[pi][j] = __expf(sc[pi][j] - m) * inv;
        if (sub == 0) {
            Sm[bP + (size_t)h * kW + w0 + pi] = m;
            Si[bP + (size_t)h * kW + w0 + pi] = inv;
        }
    }
    __syncthreads();

    // outW: thread = channel c, 32 pixel accumulators
    const int c = t;
    float acc[32];
#pragma unroll
    for (int i2 = 0; i2 < 32; i2++) acc[i2] = 0.f;
    const float* __restrict__ vrow = V + (bP + (size_t)h * kW) * kC + c;
    for (int j = 0; j < 96; j += 4) {
        float v0 = vrow[(size_t)(j + 0) * kC];
        float v1 = vrow[(size_t)(j + 1) * kC];
        float v2 = vrow[(size_t)(j + 2) * kC];
        float v3 = vrow[(size_t)(j + 3) * kC];
#pragma unroll
        for (int i2 = 0; i2 < 32; i2++) {
            float4 a4 = *(const float4*)&sc[i2][96 + j];
            acc[i2] += a4.x * v0 + a4.y * v1 + a4.z * v2 + a4.w * v3;
        }
    }
    const float gamma = gamma_p[0];
#pragma unroll
    for (int i2 = 0; i2 < 32; i2++) {
        Zb[(bP + (size_t)h * kW + w0 + i2) * 512 + s_off + c] =
            __float2bfloat16(gamma * acc[i2] + rs[c][i2]);
    }
}

// ---------------------------------------------------------------------------
// Kernel C: pass2 (one stream). grid (H/32, W, B), block 256.
// Recomputes the 96 eH scores from Q,K + stored stats (no AH buffer),
// then outH column aggregation; Zb += bf16(gamma*outH). LDS: 31.2 KB.
// ---------------------------------------------------------------------------
__global__ __launch_bounds__(256) void cc_pass2(
    const float* __restrict__ Q, const float* __restrict__ K, const float* __restrict__ V,
    const float* __restrict__ gamma_p,
    __hip_bfloat16* __restrict__ Zb, const float* __restrict__ Sm, const float* __restrict__ Si,
    int s_off)
{
    __shared__ __align__(16) float qs2[32][36];
    __shared__ __align__(16) float ks2[96][36];
    __shared__ __align__(16) float ah[32][100];
    const int ht = blockIdx.x, w = blockIdx.y, b = blockIdx.z;
    const int h0 = ht * 32;
    const int t = threadIdx.x;
    const size_t bP = (size_t)b * kP;

    for (int l = t; l < 32 * 32; l += 256) {
        int i = l >> 5, c = l & 31;
        qs2[i][c] = Q[(bP + (size_t)(h0 + i) * kW + w) * kCq + c];
    }
    for (int l = t; l < 96 * 32; l += 256) {
        int j = l >> 5, c = l & 31;
        ks2[j][c] = K[(bP + (size_t)j * kW + w) * kCq + c];
    }
    __syncthreads();

    {   // recompute eH scores + softmax weights via stats
        const int i = t & 31, jg = t >> 5;
        const float mi = Sm[bP + (size_t)(h0 + i) * kW + w];
        const float ii = Si[bP + (size_t)(h0 + i) * kW + w];
        for (int j = jg; j < 96; j += 8) {
            float dot = 0.f;
#pragma unroll
            for (int c4 = 0; c4 < 8; c4++) {
                float4 qq = *(const float4*)&qs2[i][c4 * 4];
                float4 kk = *(const float4*)&ks2[j][c4 * 4];
                dot += qq.x * kk.x + qq.y * kk.y + qq.z * kk.z + qq.w * kk.w;
            }
            ah[i][j] = (j == h0 + i) ? 0.f : __expf(dot - mi) * ii;
        }
    }
    __syncthreads();

    const int c = t;
    float acc[32];
#pragma unroll
    for (int i = 0; i < 32; i++) acc[i] = 0.f;
    const float* __restrict__ vcol = V + (bP + (size_t)w) * kC + c;
    for (int j = 0; j < 96; j += 4) {
        float v0 = vcol[(size_t)(j + 0) * kW * kC];
        float v1 = vcol[(size_t)(j + 1) * kW * kC];
        float v2 = vcol[(size_t)(j + 2) * kW * kC];
        float v3 = vcol[(size_t)(j + 3) * kW * kC];
#pragma unroll
        for (int i = 0; i < 32; i++) {
            float4 a4 = *(const float4*)&ah[i][j];
            acc[i] += a4.x * v0 + a4.y * v1 + a4.z * v2 + a4.w * v3;
        }
    }
    const float gamma = gamma_p[0];
#pragma unroll
    for (int i = 0; i < 32; i++) {
        size_t zi = (bP + (size_t)(h0 + i) * kW + w) * 512 + s_off + c;
        Zb[zi] = __float2bfloat16(__bfloat162float(Zb[zi]) + gamma * acc[i]);
    }
}

// ---------------------------------------------------------------------------
// Kernel W2: convert Wp [256][512] fp32 -> bf16 (into dead Q region of ws).
// ---------------------------------------------------------------------------
__global__ __launch_bounds__(256) void wp_convert(
    const float* __restrict__ Wp, __hip_bfloat16* __restrict__ Wpb)
{
    const int i = blockIdx.x * 256 + threadIdx.x;
    Wpb[i] = __float2bfloat16(Wp[i]);
}

// ---------------------------------------------------------------------------
// Kernel D: fused depthwise 3x3 + pointwise 512->256 (bf16 MFMA) + leaky relu.
// grid (W/32, H, B), block 256 = 4 waves.
// ---------------------------------------------------------------------------
__global__ __launch_bounds__(256) void dwpw(
    const __hip_bfloat16* __restrict__ Zb,
    const float* __restrict__ Wdw, const float* __restrict__ bd,
    const __hip_bfloat16* __restrict__ Wpb, const float* __restrict__ bp,
    float* __restrict__ out)
{
    __shared__ __align__(16) char smem[33792];
    __hip_bfloat16 (*zs)[520] = (__hip_bfloat16 (*)[520])smem;

    const int wt = blockIdx.x, h = blockIdx.y, b = blockIdx.z;
    const int w0 = wt * 32;
    const int t = threadIdx.x;
    const size_t bP = (size_t)b * kP;

    // ---- phase 1: depthwise 3x3, thread t owns channel pair (2t, 2t+1) ----
    {
        float wd0[9], wd1[9];
#pragma unroll
        for (int k = 0; k < 9; k++) {
            wd0[k] = Wdw[(size_t)(2 * t) * 9 + k];
            wd1[k] = Wdw[(size_t)(2 * t + 1) * 9 + k];
        }
        const float b0 = bd[2 * t], b1 = bd[2 * t + 1];
        const __hip_bfloat162* __restrict__ Zp =
            (const __hip_bfloat162*)Zb + bP * 256 + t;
        for (int i = 0; i < 32; i++) {
            float a0 = b0, a1 = b1;
#pragma unroll
            for (int dh = -1; dh <= 1; dh++) {
                const int hh = h + dh;
                if (hh < 0 || hh >= kH) continue;
#pragma unroll
                for (int dw = -1; dw <= 1; dw++) {
                    const int ww = w0 + i + dw;
                    if (ww < 0 || ww >= kW) continue;
                    __hip_bfloat162 z2 = Zp[(size_t)(hh * kW + ww) * 256];
                    const int k = (dh + 1) * 3 + (dw + 1);
                    a0 += wd0[k] * __bfloat162float(z2.x);
                    a1 += wd1[k] * __bfloat162float(z2.y);
                }
            }
            __hip_bfloat162 pz;
            pz.x = __float2bfloat16(a0);
            pz.y = __float2bfloat16(a1);
            ((__hip_bfloat162*)&zs[i][0])[t] = pz;
        }
    }
    __syncthreads();

    // ---- phase 2: pointwise MFMA ----
    const int l = t & 63, wv = t >> 6;
    const int lo16 = l & 15, q = l >> 4;   // quad 0..3

    f32x4 acc[2][4];
#pragma unroll
    for (int mt = 0; mt < 2; mt++)
#pragma unroll
        for (int nt = 0; nt < 4; nt++) acc[mt][nt] = (f32x4)0.f;

    const bf16x8* __restrict__ Bb[4];
#pragma unroll
    for (int nt = 0; nt < 4; nt++)
        Bb[nt] = (const bf16x8*)(Wpb + (size_t)(wv * 64 + nt * 16 + lo16) * 512);

    for (int kc = 0; kc < 16; kc++) {
        bf16x8 a0 = *(const bf16x8*)&zs[lo16][kc * 32 + q * 8];
        bf16x8 a1 = *(const bf16x8*)&zs[16 + lo16][kc * 32 + q * 8];
#pragma unroll
        for (int nt = 0; nt < 4; nt++) {
            bf16x8 bf = Bb[nt][kc * 4 + q];
            acc[0][nt] = __builtin_amdgcn_mfma_f32_16x16x32_bf16(a0, bf, acc[0][nt], 0, 0, 0);
            acc[1][nt] = __builtin_amdgcn_mfma_f32_16x16x32_bf16(a1, bf, acc[1][nt], 0, 0, 0);
        }
    }
    __syncthreads();   // all waves done reading zs; reuse smem for transpose

    // ---- phase 3: bias + leaky relu, LDS transpose, coalesced stores ----
    float* os = (float*)smem + (size_t)wv * 64 * 33;   // per-wave [64 o][33]
#pragma unroll
    for (int nt = 0; nt < 4; nt++) {
        const int ol = nt * 16 + lo16;
        const float bias = bp[wv * 64 + ol];
#pragma unroll
        for (int mt = 0; mt < 2; mt++) {
#pragma unroll
            for (int r = 0; r < 4; r++) {
                float v = acc[mt][nt][r] + bias;
                v = v > 0.f ? v : 0.01f * v;
                os[ol * 33 + mt * 16 + q * 4 + r] = v;
            }
        }
    }
    __syncthreads();
    const int px = l & 31, oh = l >> 5;    // 2 o-rows per iteration
    for (int j = 0; j < 32; j++) {
        const int ol = j * 2 + oh;
        out[((size_t)b * 256 + wv * 64 + ol) * kP + (size_t)h * kW + w0 + px] =
            os[ol * 33 + px];
    }
}

// ---------------------------------------------------------------------------
extern "C" void kernel_launch(void* const* d_in, const int* in_sizes, int n_in,
                              void* d_out, int out_size, void* d_ws, size_t ws_size,
                              hipStream_t stream)
{
    const float* x   = (const float*)d_in[0];
    const float* y   = (const float*)d_in[1];
    const float* Wq  = (const float*)d_in[2];
    const float* bq  = (const float*)d_in[3];
    const float* Wk  = (const float*)d_in[4];
    const float* bk  = (const float*)d_in[5];
    const float* Wv  = (const float*)d_in[6];
    const float* bv  = (const float*)d_in[7];
    const float* g1  = (const float*)d_in[8];
    const float* g2  = (const float*)d_in[9];
    const float* Wdw = (const float*)d_in[10];
    const float* bd  = (const float*)d_in[11];
    const float* Wp  = (const float*)d_in[12];
    const float* bp  = (const float*)d_in[13];
    float* out = (float*)d_out;

    // Workspace layout (95 MB total, same as the passing round-3 layout):
    //   Zb  : bf16 [8][9216][512]  = 75,497,472 B
    //   Q,K : fp32 [8][9216][32]   =  9,437,184 B each  (reused per stream)
    //   Sm,Si: fp32 [8][9216]      =    294,912 B each  (softmax stats)
    // V (fp32 [8][9216][256] = 75.5 MB) lives in d_out until dwpw.
    // Wqkb (32 KB) + Wvb (128 KB) live in the Sm region, which is dead at
    // qkv time (pass1 writes Sm/Si AFTER qkv) -> re-converted per stream.
    // Wpb (bf16, 256 KB) reuses the Q region after the last cc_pass2.
    char* wsb = (char*)d_ws;
    __hip_bfloat16* Zb = (__hip_bfloat16*)wsb;
    float* Q  = (float*)(wsb + 75497472);
    float* K  = (float*)(wsb + 75497472 + 9437184);
    float* Sm = (float*)(wsb + 75497472 + 2 * 9437184);
    float* Si = (float*)(wsb + 75497472 + 2 * 9437184 + 294912);
    __hip_bfloat16* Wqkb = (__hip_bfloat16*)Sm;            // 32 KB
    __hip_bfloat16* Wvb  = (__hip_bfloat16*)(((char*)Sm) + 32768);  // 128 KB
    __hip_bfloat16* Wpb  = (__hip_bfloat16*)(wsb + 75497472);       // dead Q region
    float* V  = out;

    // stream 1: q,k from x; v from y; residual x; channels [0,256)
    hipLaunchKernelGGL(w_convert, dim3(320), dim3(256), 0, stream,
                       Wq, Wk, Wv, Wqkb, Wvb);
    hipLaunchKernelGGL(qkv_mfma, dim3(kP / 64, kB), dim3(256), 0, stream,
                       x, y, Wqkb, Wvb, bq, bk, bv, Q, K, V);
    hipLaunchKernelGGL(cc_pass1, dim3(kW / 32, kH, kB), dim3(256), 0, stream,
                       Q, K, V, x, g1, Zb, Sm, Si, 0);
    hipLaunchKernelGGL(cc_pass2, dim3(kH / 32, kW, kB), dim3(256), 0, stream,
                       Q, K, V, g1, Zb, Sm, Si, 0);
    // stream 2: q,k from y; v from x; residual y; channels [256,512)
    hipLaunchKernelGGL(w_convert, dim3(320), dim3(256), 0, stream,
                       Wq, Wk, Wv, Wqkb, Wvb);
    hipLaunchKernelGGL(qkv_mfma, dim3(kP / 64, kB), dim3(256), 0, stream,
                       y, x, Wqkb, Wvb, bq, bk, bv, Q, K, V);
    hipLaunchKernelGGL(cc_pass1, dim3(kW / 32, kH, kB), dim3(256), 0, stream,
                       Q, K, V, y, g2, Zb, Sm, Si, 256);
    hipLaunchKernelGGL(cc_pass2, dim3(kH / 32, kW, kB), dim3(256), 0, stream,
                       Q, K, V, g2, Zb, Sm, Si, 256);
    // convert Wp to bf16 (Q region is dead now)
    hipLaunchKernelGGL(wp_convert, dim3(512), dim3(256), 0, stream, Wp, Wpb);
    // fused depthwise + pointwise MFMA + leaky relu (overwrites d_out)
    hipLaunchKernelGGL(dwpw, dim3(kW / 32, kH, kB), dim3(256), 0, stream,
                       Zb, Wdw, bd, Wpb, bp, out);
}

// Round 5
// 1336.163 us; speedup vs baseline: 3.0519x; 1.0780x over previous
//
#include <hip/hip_runtime.h>
#include <hip/hip_bf16.h>

constexpr int kB  = 8;
constexpr int kC  = 256;
constexpr int kCq = 32;
constexpr int kH  = 96;
constexpr int kW  = 96;
constexpr int kP  = kH * kW;      // 9216
constexpr float kNEG = -1e30f;

using bf16x8 = __attribute__((ext_vector_type(8))) short;
using f32x4  = __attribute__((ext_vector_type(4))) float;

// ---------------------------------------------------------------------------
// Kernel W1: convert Wq+Wk -> Wqkb [64][256] bf16, Wv -> Wvb [256][256] bf16.
// grid 320 x 256.
// ---------------------------------------------------------------------------
__global__ __launch_bounds__(256) void w_convert(
    const float* __restrict__ Wq, const float* __restrict__ Wk,
    const float* __restrict__ Wv,
    __hip_bfloat16* __restrict__ Wqkb, __hip_bfloat16* __restrict__ Wvb)
{
    const int i = blockIdx.x * 256 + threadIdx.x;
    if (i < 8192)       Wqkb[i] = __float2bfloat16(Wq[i]);
    else if (i < 16384) Wqkb[i] = __float2bfloat16(Wk[i - 8192]);
    else                Wvb[i - 16384] = __float2bfloat16(Wv[i - 16384]);
}

// ---------------------------------------------------------------------------
// Kernel A: q/k/v projection GEMM via bf16 MFMA, no LDS.
// D[m=o][n=p]: A = weights (bf16, contiguous frags), B = input (built from
// 8 channel-strided fp32 loads per lane; lanes n=0..15 -> 64B coalesced runs).
// grid (144, B), block 256 = 4 waves; per wave 16 pixels x 320 outputs.
// D: col=lane&15 = pixel, row=quad*4+reg = o -> float4 stores along channel.
// ---------------------------------------------------------------------------
__global__ __launch_bounds__(256) void qkv_mfma(
    const float* __restrict__ in_qk, const float* __restrict__ in_v,
    const __hip_bfloat16* __restrict__ Wqkb, const __hip_bfloat16* __restrict__ Wvb,
    const float* __restrict__ bq, const float* __restrict__ bk,
    const float* __restrict__ bv,
    float* __restrict__ Q, float* __restrict__ K, float* __restrict__ V)
{
    const int b = blockIdx.y;
    const int t = threadIdx.x;
    const int wv = t >> 6, l = t & 63;
    const int n = l & 15, q = l >> 4;            // n = pixel col, q = quad
    const int p = blockIdx.x * 64 + wv * 16 + n; // this lane's pixel
    const size_t bP = (size_t)b * kP;

    const float* __restrict__ xq = in_qk + (size_t)b * kC * kP + p;
    const float* __restrict__ xv = in_v  + (size_t)b * kC * kP + p;

    f32x4 acc[20];
#pragma unroll
    for (int i = 0; i < 20; i++) acc[i] = (f32x4)0.f;

    for (int kc = 0; kc < 8; kc++) {
        const int c0 = kc * 32 + q * 8;          // this lane's k-slice base
        // ---- B fragments: 16 scalar fp32 loads (all issued up front) ----
        float fq[8], fv[8];
#pragma unroll
        for (int j = 0; j < 8; j++) fq[j] = xq[(size_t)(c0 + j) * kP];
#pragma unroll
        for (int j = 0; j < 8; j++) fv[j] = xv[(size_t)(c0 + j) * kP];
        union { bf16x8 v; __hip_bfloat16 h[8]; } bfq, bfv;
#pragma unroll
        for (int j = 0; j < 8; j++) bfq.h[j] = __float2bfloat16(fq[j]);
#pragma unroll
        for (int j = 0; j < 8; j++) bfv.h[j] = __float2bfloat16(fv[j]);

        // ---- A fragments from bf16 weights + MFMA ----
#pragma unroll
        for (int mt = 0; mt < 4; mt++) {
            bf16x8 a = *(const bf16x8*)(Wqkb + ((mt * 16 + n) << 8) + c0);
            acc[mt] = __builtin_amdgcn_mfma_f32_16x16x32_bf16(a, bfq.v, acc[mt], 0, 0, 0);
        }
#pragma unroll
        for (int mt = 0; mt < 16; mt++) {
            bf16x8 a = *(const bf16x8*)(Wvb + ((mt * 16 + n) << 8) + c0);
            acc[4 + mt] = __builtin_amdgcn_mfma_f32_16x16x32_bf16(a, bfv.v, acc[4 + mt], 0, 0, 0);
        }
    }

    // ---- epilogue: bias + float4 stores (pixel-major Q/K/V) ----
    float* __restrict__ Qp = Q + (bP + p) * kCq;
    float* __restrict__ Kp = K + (bP + p) * kCq;
    float* __restrict__ Vp = V + (bP + p) * kC;
#pragma unroll
    for (int mt = 0; mt < 2; mt++) {
        float4 bias = *(const float4*)&bq[mt * 16 + q * 4];
        float4 r = { acc[mt][0] + bias.x, acc[mt][1] + bias.y,
                     acc[mt][2] + bias.z, acc[mt][3] + bias.w };
        *(float4*)&Qp[mt * 16 + q * 4] = r;
    }
#pragma unroll
    for (int mt = 2; mt < 4; mt++) {
        float4 bias = *(const float4*)&bk[(mt - 2) * 16 + q * 4];
        float4 r = { acc[mt][0] + bias.x, acc[mt][1] + bias.y,
                     acc[mt][2] + bias.z, acc[mt][3] + bias.w };
        *(float4*)&Kp[(mt - 2) * 16 + q * 4] = r;
    }
#pragma unroll
    for (int mt = 0; mt < 16; mt++) {
        float4 bias = *(const float4*)&bv[mt * 16 + q * 4];
        float4 r = { acc[4 + mt][0] + bias.x, acc[4 + mt][1] + bias.y,
                     acc[4 + mt][2] + bias.z, acc[4 + mt][3] + bias.w };
        *(float4*)&Vp[mt * 16 + q * 4] = r;
    }
}

// ---------------------------------------------------------------------------
// Kernel B: pass1 (one stream). grid (W/32, H, B), block 256.
// 192 scores -> softmax -> store (m, 1/sum) stats -> outW + epilogue:
// Zb[b][p][s_off+c] = bf16(gamma*outW + residual).  LDS: 63.1 KB.
// ---------------------------------------------------------------------------
__global__ __launch_bounds__(256) void cc_pass1(
    const float* __restrict__ Q, const float* __restrict__ K, const float* __restrict__ V,
    const float* __restrict__ res_in, const float* __restrict__ gamma_p,
    __hip_bfloat16* __restrict__ Zb, float* __restrict__ Sm, float* __restrict__ Si,
    int s_off)
{
    __shared__ __align__(16) float qs[32][33];
    __shared__ __align__(16) float sc[32][196];
    __shared__ __align__(16) float rs[256][33];
    const int wt = blockIdx.x, h = blockIdx.y, b = blockIdx.z;
    const int w0 = wt * 32;
    const int t = threadIdx.x;
    const size_t bP = (size_t)b * kP;

    for (int l = t; l < 32 * 32; l += 256) {
        int i = l >> 5, c = l & 31;
        qs[i][c] = Q[(bP + (size_t)h * kW + w0 + i) * kCq + c];
    }
    const float* __restrict__ res = res_in + (size_t)b * kC * kP + (size_t)h * kW + w0;
    for (int l = t; l < 256 * 32; l += 256) {
        int c2 = l >> 5, i2 = l & 31;
        rs[c2][i2] = res[(size_t)c2 * kP + i2];
    }
    __syncthreads();

    {   // scores: i = pixel-in-tile, sg = score slice
        const int i = t & 31, sg = t >> 5;
        for (int jj = sg; jj < 192; jj += 8) {
            const float* krow;
            if (jj < 96) krow = K + (bP + (size_t)jj * kW + w0 + i) * kCq;     // eH
            else         krow = K + (bP + (size_t)h * kW + (jj - 96)) * kCq;   // eW
            const float4* k4 = (const float4*)krow;
            float dot = 0.f;
#pragma unroll
            for (int c4 = 0; c4 < 8; c4++) {
                float4 kk = k4[c4];
                dot += kk.x * qs[i][c4 * 4 + 0] + kk.y * qs[i][c4 * 4 + 1]
                     + kk.z * qs[i][c4 * 4 + 2] + kk.w * qs[i][c4 * 4 + 3];
            }
            if (jj == h) dot = kNEG;   // eH diagonal mask (jj<96 range only, h<96)
            sc[i][jj] = dot;
        }
    }
    __syncthreads();

    {   // softmax over 192, 8 threads per pixel; record stats for pass2
        const int pi = t >> 3, sub = t & 7;
        float m = -3.0e38f;
        for (int j = sub; j < 192; j += 8) m = fmaxf(m, sc[pi][j]);
#pragma unroll
        for (int k = 1; k < 8; k <<= 1) m = fmaxf(m, __shfl_xor(m, k, 8));
        float ss = 0.f;
        for (int j = sub; j < 192; j += 8) ss += __expf(sc[pi][j] - m);
#pragma unroll
        for (int k = 1; k < 8; k <<= 1) ss += __shfl_xor(ss, k, 8);
        float inv = 1.0f / ss;
        for (int j = sub; j < 192; j += 8) sc[pi][j] = __expf(sc[pi][j] - m) * inv;
        if (sub == 0) {
            Sm[bP + (size_t)h * kW + w0 + pi] = m;
            Si[bP + (size_t)h * kW + w0 + pi] = inv;
        }
    }
    __syncthreads();

    // outW: thread = channel c, 32 pixel accumulators
    const int c = t;
    float acc[32];
#pragma unroll
    for (int i2 = 0; i2 < 32; i2++) acc[i2] = 0.f;
    const float* __restrict__ vrow = V + (bP + (size_t)h * kW) * kC + c;
    for (int j = 0; j < 96; j += 4) {
        float v0 = vrow[(size_t)(j + 0) * kC];
        float v1 = vrow[(size_t)(j + 1) * kC];
        float v2 = vrow[(size_t)(j + 2) * kC];
        float v3 = vrow[(size_t)(j + 3) * kC];
#pragma unroll
        for (int i2 = 0; i2 < 32; i2++) {
            float4 a4 = *(const float4*)&sc[i2][96 + j];
            acc[i2] += a4.x * v0 + a4.y * v1 + a4.z * v2 + a4.w * v3;
        }
    }
    const float gamma = gamma_p[0];
#pragma unroll
    for (int i2 = 0; i2 < 32; i2++) {
        Zb[(bP + (size_t)h * kW + w0 + i2) * 512 + s_off + c] =
            __float2bfloat16(gamma * acc[i2] + rs[c][i2]);
    }
}

// ---------------------------------------------------------------------------
// Kernel C: pass2 (one stream). grid (H/32, W, B), block 256.
// Recomputes the 96 eH scores from Q,K + stored stats (no AH buffer),
// then outH column aggregation; Zb += bf16(gamma*outH). LDS: 31.2 KB.
// ---------------------------------------------------------------------------
__global__ __launch_bounds__(256) void cc_pass2(
    const float* __restrict__ Q, const float* __restrict__ K, const float* __restrict__ V,
    const float* __restrict__ gamma_p,
    __hip_bfloat16* __restrict__ Zb, const float* __restrict__ Sm, const float* __restrict__ Si,
    int s_off)
{
    __shared__ __align__(16) float qs2[32][36];
    __shared__ __align__(16) float ks2[96][36];
    __shared__ __align__(16) float ah[32][100];
    const int ht = blockIdx.x, w = blockIdx.y, b = blockIdx.z;
    const int h0 = ht * 32;
    const int t = threadIdx.x;
    const size_t bP = (size_t)b * kP;

    for (int l = t; l < 32 * 32; l += 256) {
        int i = l >> 5, c = l & 31;
        qs2[i][c] = Q[(bP + (size_t)(h0 + i) * kW + w) * kCq + c];
    }
    for (int l = t; l < 96 * 32; l += 256) {
        int j = l >> 5, c = l & 31;
        ks2[j][c] = K[(bP + (size_t)j * kW + w) * kCq + c];
    }
    __syncthreads();

    {   // recompute eH scores + softmax weights via stats
        const int i = t & 31, jg = t >> 5;
        const float mi = Sm[bP + (size_t)(h0 + i) * kW + w];
        const float ii = Si[bP + (size_t)(h0 + i) * kW + w];
        for (int j = jg; j < 96; j += 8) {
            float dot = 0.f;
#pragma unroll
            for (int c4 = 0; c4 < 8; c4++) {
                float4 qq = *(const float4*)&qs2[i][c4 * 4];
                float4 kk = *(const float4*)&ks2[j][c4 * 4];
                dot += qq.x * kk.x + qq.y * kk.y + qq.z * kk.z + qq.w * kk.w;
            }
            ah[i][j] = (j == h0 + i) ? 0.f : __expf(dot - mi) * ii;
        }
    }
    __syncthreads();

    const int c = t;
    float acc[32];
#pragma unroll
    for (int i = 0; i < 32; i++) acc[i] = 0.f;
    const float* __restrict__ vcol = V + (bP + (size_t)w) * kC + c;
    for (int j = 0; j < 96; j += 4) {
        float v0 = vcol[(size_t)(j + 0) * kW * kC];
        float v1 = vcol[(size_t)(j + 1) * kW * kC];
        float v2 = vcol[(size_t)(j + 2) * kW * kC];
        float v3 = vcol[(size_t)(j + 3) * kW * kC];
#pragma unroll
        for (int i = 0; i < 32; i++) {
            float4 a4 = *(const float4*)&ah[i][j];
            acc[i] += a4.x * v0 + a4.y * v1 + a4.z * v2 + a4.w * v3;
        }
    }
    const float gamma = gamma_p[0];
#pragma unroll
    for (int i = 0; i < 32; i++) {
        size_t zi = (bP + (size_t)(h0 + i) * kW + w) * 512 + s_off + c;
        Zb[zi] = __float2bfloat16(__bfloat162float(Zb[zi]) + gamma * acc[i]);
    }
}

// ---------------------------------------------------------------------------
// Kernel W2: convert Wp [256][512] fp32 -> bf16 (into dead Q region of ws).
// ---------------------------------------------------------------------------
__global__ __launch_bounds__(256) void wp_convert(
    const float* __restrict__ Wp, __hip_bfloat16* __restrict__ Wpb)
{
    const int i = blockIdx.x * 256 + threadIdx.x;
    Wpb[i] = __float2bfloat16(Wp[i]);
}

// ---------------------------------------------------------------------------
// Kernel D: fused depthwise 3x3 + pointwise 512->256 (bf16 MFMA) + leaky relu.
// grid (W/32, H, B), block 256 = 4 waves.
// Phase 1 (v2): per thread (channel pair 2t,2t+1), 4 batches of 8 px; each
// batch issues its full 10-col x 3-row window (30 independent loads) before
// any FMA -> ~30 outstanding loads/wave (MLP) instead of 2-4.
// ---------------------------------------------------------------------------
__global__ __launch_bounds__(256) void dwpw(
    const __hip_bfloat16* __restrict__ Zb,
    const float* __restrict__ Wdw, const float* __restrict__ bd,
    const __hip_bfloat16* __restrict__ Wpb, const float* __restrict__ bp,
    float* __restrict__ out)
{
    __shared__ __align__(16) char smem[33792];
    __hip_bfloat16 (*zs)[520] = (__hip_bfloat16 (*)[520])smem;

    const int wt = blockIdx.x, h = blockIdx.y, b = blockIdx.z;
    const int w0 = wt * 32;
    const int t = threadIdx.x;
    const size_t bP = (size_t)b * kP;

    // ---- phase 1: depthwise 3x3, batched-MLP version ----
    {
        float wd0[9], wd1[9];
#pragma unroll
        for (int k = 0; k < 9; k++) {
            wd0[k] = Wdw[(size_t)(2 * t) * 9 + k];
            wd1[k] = Wdw[(size_t)(2 * t + 1) * 9 + k];
        }
        const float b0 = bd[2 * t], b1 = bd[2 * t + 1];
        const __hip_bfloat162* __restrict__ Zp =
            (const __hip_bfloat162*)Zb + bP * 256 + t;
        const bool rvm = (h > 0), rvp = (h < kH - 1);

#pragma unroll
        for (int j0 = 0; j0 < 32; j0 += 8) {
            // load + convert the whole 10x3 window for this 8-px batch
            float2 wf[10][3];
#pragma unroll
            for (int col = 0; col < 10; col++) {
                const int ww = w0 + j0 - 1 + col;
                const bool cv = (ww >= 0) && (ww < kW);
#pragma unroll
                for (int r = 0; r < 3; r++) {
                    const bool v = cv && (r == 1 || (r == 0 ? rvm : rvp));
                    __hip_bfloat162 z2;
                    z2.x = __ushort_as_bfloat16(0);
                    z2.y = __ushort_as_bfloat16(0);
                    if (v) z2 = Zp[(size_t)((h + r - 1) * kW + ww) * 256];
                    wf[col][r] = __bfloat1622float2(z2);
                }
            }
            // compute 8 px from registers
#pragma unroll
            for (int j = 0; j < 8; j++) {
                float a0 = b0, a1 = b1;
#pragma unroll
                for (int r = 0; r < 3; r++) {
#pragma unroll
                    for (int dw = 0; dw < 3; dw++) {
                        const float2 z = wf[j + dw][r];
                        const int k = r * 3 + dw;
                        a0 += wd0[k] * z.x;
                        a1 += wd1[k] * z.y;
                    }
                }
                __hip_bfloat162 pz;
                pz.x = __float2bfloat16(a0);
                pz.y = __float2bfloat16(a1);
                ((__hip_bfloat162*)&zs[j0 + j][0])[t] = pz;
            }
        }
    }
    __syncthreads();

    // ---- phase 2: pointwise MFMA ----
    const int l = t & 63, wv = t >> 6;
    const int lo16 = l & 15, q = l >> 4;   // quad 0..3

    f32x4 acc[2][4];
#pragma unroll
    for (int mt = 0; mt < 2; mt++)
#pragma unroll
        for (int nt = 0; nt < 4; nt++) acc[mt][nt] = (f32x4)0.f;

    const bf16x8* __restrict__ Bb[4];
#pragma unroll
    for (int nt = 0; nt < 4; nt++)
        Bb[nt] = (const bf16x8*)(Wpb + (size_t)(wv * 64 + nt * 16 + lo16) * 512);

    for (int kc = 0; kc < 16; kc++) {
        bf16x8 a0 = *(const bf16x8*)&zs[lo16][kc * 32 + q * 8];
        bf16x8 a1 = *(const bf16x8*)&zs[16 + lo16][kc * 32 + q * 8];
#pragma unroll
        for (int nt = 0; nt < 4; nt++) {
            bf16x8 bf = Bb[nt][kc * 4 + q];
            acc[0][nt] = __builtin_amdgcn_mfma_f32_16x16x32_bf16(a0, bf, acc[0][nt], 0, 0, 0);
            acc[1][nt] = __builtin_amdgcn_mfma_f32_16x16x32_bf16(a1, bf, acc[1][nt], 0, 0, 0);
        }
    }
    __syncthreads();   // all waves done reading zs; reuse smem for transpose

    // ---- phase 3: bias + leaky relu, LDS transpose, coalesced stores ----
    float* os = (float*)smem + (size_t)wv * 64 * 33;   // per-wave [64 o][33]
#pragma unroll
    for (int nt = 0; nt < 4; nt++) {
        const int ol = nt * 16 + lo16;
        const float bias = bp[wv * 64 + ol];
#pragma unroll
        for (int mt = 0; mt < 2; mt++) {
#pragma unroll
            for (int r = 0; r < 4; r++) {
                float v = acc[mt][nt][r] + bias;
                v = v > 0.f ? v : 0.01f * v;
                os[ol * 33 + mt * 16 + q * 4 + r] = v;
            }
        }
    }
    __syncthreads();
    const int px = l & 31, oh = l >> 5;    // 2 o-rows per iteration
    for (int j = 0; j < 32; j++) {
        const int ol = j * 2 + oh;
        out[((size_t)b * 256 + wv * 64 + ol) * kP + (size_t)h * kW + w0 + px] =
            os[ol * 33 + px];
    }
}

// ---------------------------------------------------------------------------
extern "C" void kernel_launch(void* const* d_in, const int* in_sizes, int n_in,
                              void* d_out, int out_size, void* d_ws, size_t ws_size,
                              hipStream_t stream)
{
    const float* x   = (const float*)d_in[0];
    const float* y   = (const float*)d_in[1];
    const float* Wq  = (const float*)d_in[2];
    const float* bq  = (const float*)d_in[3];
    const float* Wk  = (const float*)d_in[4];
    const float* bk  = (const float*)d_in[5];
    const float* Wv  = (const float*)d_in[6];
    const float* bv  = (const float*)d_in[7];
    const float* g1  = (const float*)d_in[8];
    const float* g2  = (const float*)d_in[9];
    const float* Wdw = (const float*)d_in[10];
    const float* bd  = (const float*)d_in[11];
    const float* Wp  = (const float*)d_in[12];
    const float* bp  = (const float*)d_in[13];
    float* out = (float*)d_out;

    // Workspace layout (95 MB total, same as the passing round-3/4 layout):
    //   Zb  : bf16 [8][9216][512]  = 75,497,472 B
    //   Q,K : fp32 [8][9216][32]   =  9,437,184 B each  (reused per stream)
    //   Sm,Si: fp32 [8][9216]      =    294,912 B each  (softmax stats)
    // V (fp32 [8][9216][256] = 75.5 MB) lives in d_out until dwpw.
    // Wqkb (32 KB) + Wvb (128 KB) live in the Sm region, which is dead at
    // qkv time (pass1 writes Sm/Si AFTER qkv) -> re-converted per stream.
    // Wpb (bf16, 256 KB) reuses the Q region after the last cc_pass2.
    char* wsb = (char*)d_ws;
    __hip_bfloat16* Zb = (__hip_bfloat16*)wsb;
    float* Q  = (float*)(wsb + 75497472);
    float* K  = (float*)(wsb + 75497472 + 9437184);
    float* Sm = (float*)(wsb + 75497472 + 2 * 9437184);
    float* Si = (float*)(wsb + 75497472 + 2 * 9437184 + 294912);
    __hip_bfloat16* Wqkb = (__hip_bfloat16*)Sm;            // 32 KB
    __hip_bfloat16* Wvb  = (__hip_bfloat16*)(((char*)Sm) + 32768);  // 128 KB
    __hip_bfloat16* Wpb  = (__hip_bfloat16*)(wsb + 75497472);       // dead Q region
    float* V  = out;

    // stream 1: q,k from x; v from y; residual x; channels [0,256)
    hipLaunchKernelGGL(w_convert, dim3(320), dim3(256), 0, stream,
                       Wq, Wk, Wv, Wqkb, Wvb);
    hipLaunchKernelGGL(qkv_mfma, dim3(kP / 64, kB), dim3(256), 0, stream,
                       x, y, Wqkb, Wvb, bq, bk, bv, Q, K, V);
    hipLaunchKernelGGL(cc_pass1, dim3(kW / 32, kH, kB), dim3(256), 0, stream,
                       Q, K, V, x, g1, Zb, Sm, Si, 0);
    hipLaunchKernelGGL(cc_pass2, dim3(kH / 32, kW, kB), dim3(256), 0, stream,
                       Q, K, V, g1, Zb, Sm, Si, 0);
    // stream 2: q,k from y; v from x; residual y; channels [256,512)
    hipLaunchKernelGGL(w_convert, dim3(320), dim3(256), 0, stream,
                       Wq, Wk, Wv, Wqkb, Wvb);
    hipLaunchKernelGGL(qkv_mfma, dim3(kP / 64, kB), dim3(256), 0, stream,
                       y, x, Wqkb, Wvb, bq, bk, bv, Q, K, V);
    hipLaunchKernelGGL(cc_pass1, dim3(kW / 32, kH, kB), dim3(256), 0, stream,
                       Q, K, V, y, g2, Zb, Sm, Si, 256);
    hipLaunchKernelGGL(cc_pass2, dim3(kH / 32, kW, kB), dim3(256), 0, stream,
                       Q, K, V, g2, Zb, Sm, Si, 256);
    // convert Wp to bf16 (Q region is dead now)
    hipLaunchKernelGGL(wp_convert, dim3(512), dim3(256), 0, stream, Wp, Wpb);
    // fused depthwise + pointwise MFMA + leaky relu (overwrites d_out)
    hipLaunchKernelGGL(dwpw, dim3(kW / 32, kH, kB), dim3(256), 0, stream,
                       Zb, Wdw, bd, Wpb, bp, out);
}